// Round 12
// baseline (889.050 us; speedup 1.0000x reference)
//
#include <hip/hip_runtime.h>

#define NTOK 32768
#define NE   2048
#define EDIM 128
#define NQ   4

#define TOKT 64                  // tokens per block
#define CHCODES 64               // codes per staged chunk (16 KB bf16)
#define NCHUNK (NE / CHCODES)    // 32
#define NHC 64                   // half-chunks (32 codes each)
#define WLCAP 512
#define MARGIN_S 0.25f           // s-space margin (~3x the bf16 error bound)

typedef __attribute__((ext_vector_type(8))) short short8v;   // 8 bf16
typedef __attribute__((ext_vector_type(4))) float f32x4;

__device__ __forceinline__ unsigned short bf16rne(float x) {
    unsigned u = __float_as_uint(x);
    unsigned r = 0x7FFFu + ((u >> 16) & 1u);
    return (unsigned short)((u + r) >> 16);
}

// monotone total-order encoding of float (f1<f2 <=> enc(f1)<enc(f2))
__device__ __forceinline__ unsigned enc32f(float f) {
    unsigned u = __float_as_uint(f);
    return u ^ ((unsigned)((int)u >> 31) | 0x80000000u);
}
__device__ __forceinline__ unsigned short enc16ceil(float f) {
    return (unsigned short)((enc32f(f) >> 16) + 1);   // stored >= true
}

__device__ __forceinline__ void gld16(const void* g, const void* l) {
    __builtin_amdgcn_global_load_lds(
        (const __attribute__((address_space(1))) unsigned int*)g,
        (__attribute__((address_space(3))) unsigned int*)l, 16, 0, 0);
}

#define MFMA_BF16 __builtin_amdgcn_mfma_f32_16x16x32_bf16

// ---------------------------------------------------------------------------
// prep: per-code fp32 norms (identical serial chain to rounds 1-11) + bf16
// convert with dim-XOR swizzle (dim ^ ((code&7)<<3)) + zero loss accumulator.
// ---------------------------------------------------------------------------
__global__ __launch_bounds__(256) void prep_kernel(
    const float* __restrict__ cb, unsigned short* __restrict__ cb16s,
    float* __restrict__ cnorm, float* __restrict__ loss_accum)
{
    const int row = blockIdx.x * 256 + threadIdx.x;   // 0..NQ*NE-1
    if (row == 0) *loss_accum = 0.0f;
    const float* src = cb + (size_t)row * EDIM;
    unsigned short* dst = cb16s + (size_t)row * EDIM;
    const int swz8 = (row & 7) << 3;
    float s = 0.0f;
#pragma unroll
    for (int j = 0; j < EDIM / 4; ++j) {
        float4 v = ((const float4*)src)[j];
        s += v.x * v.x; s += v.y * v.y; s += v.z * v.z; s += v.w * v.w;
        ushort4 o;
        o.x = bf16rne(v.x); o.y = bf16rne(v.y);
        o.z = bf16rne(v.z); o.w = bf16rne(v.w);
        *(ushort4*)(dst + ((j * 4) ^ swz8)) = o;
    }
    cnorm[row] = s;
}

// ---------------------------------------------------------------------------
// One VQ level. SINGLE bf16-MFMA pass (s = dot - cn/2 via C-init = -cn/2)
// + per-(token,half-chunk) max table (chm, u16 ceil-encoded) + qualification
// scan + exact-fp32 refine over qualifying half-chunks with lex-min via
// 64-bit atomicMin. 256 thr / 4 waves; wave (rh,chalf) = 32 tokens x 1024
// codes; ~75 KB LDS -> 2 blocks/CU.
// ---------------------------------------------------------------------------
__global__ __launch_bounds__(256, 2) void vq_level_kernel(
    const float* __restrict__ rin,
    const float* __restrict__ cbF,          // fp32 codebook (refine + gather)
    const unsigned short* __restrict__ cbL, // bf16 swizzled codebook (level)
    const float* __restrict__ cnorm,        // [NE]
    float* __restrict__ rout,
    float* __restrict__ xq,
    float* __restrict__ idx_out,
    float* __restrict__ loss_accum,
    int level, int first)
{
    __shared__ __align__(16) float Af[TOKT][132];                  // 33792 B
    __shared__ __align__(16) unsigned short Bs[2][CHCODES * EDIM]; // 32768 B
    __shared__ unsigned short chm[TOKT * NHC];                     // 8192 B
    __shared__ float rns[TOKT];

    // overlays inside Bs (phase-disjoint with staging):
    float* part = (float*)&Bs[1][0];                    // [4][64], pre-loop
    char*  ov   = (char*)&Bs[0][0];                     // post-pass1 region
    unsigned long long* best = (unsigned long long*)ov; // [64]  @0
    int*   wl    = (int*)(ov + 512);                    // [512] @512
    int*   wcnt  = (int*)(ov + 2560);                   //       @2560
    float* smaxs = (float*)(ov + 2576);                 // [64]  @2576
    float* mdw   = (float*)(ov + 2832);                 // [2][64] @2832
    int*   idx_s = (int*)(ov + 3344);                   // [64]  @3344
    float* lsum  = (float*)(ov + 3600);                 // [256] @3600

    const int t     = threadIdx.x;
    const int tok0  = blockIdx.x * TOKT;
    const int w     = t >> 6;
    const int rh    = w >> 1;         // token half
    const int chalf = w & 1;          // code half within each chunk
    const int cl    = t & 15;         // MFMA col lane
    const int lg    = (t & 63) >> 4;  // k-group

    // ---- stage residual row-major + partial norms (rounds 1-11 chain) ----
    {
        const int tok = t & 63;
        const int dg  = t >> 6;
        float s = 0.0f;
#pragma unroll
        for (int j = 0; j < 8; ++j) {
            const int d0 = dg * 32 + j * 4;
            float4 v = *(const float4*)(rin + (size_t)(tok0 + tok) * EDIM + d0);
            *(float4*)&Af[tok][d0] = v;
            s += v.x * v.x; s += v.y * v.y; s += v.z * v.z; s += v.w * v.w;
        }
        part[dg * TOKT + tok] = s;
    }
    __syncthreads();
    if (t < TOKT)
        rns[t] = ((part[t] + part[TOKT + t]) + part[2 * TOKT + t])
                 + part[3 * TOKT + t];

    // ---- A fragments: 2 row-tiles x 4 kt ----
    short8v a00, a01, a02, a03, a10, a11, a12, a13;
#define LDA(AF, AROW, KT) { \
    float4 p0 = *(const float4*)&Af[AROW][(KT) * 32 + lg * 8]; \
    float4 p1 = *(const float4*)&Af[AROW][(KT) * 32 + lg * 8 + 4]; \
    AF[0] = (short)bf16rne(p0.x); AF[1] = (short)bf16rne(p0.y); \
    AF[2] = (short)bf16rne(p0.z); AF[3] = (short)bf16rne(p0.w); \
    AF[4] = (short)bf16rne(p1.x); AF[5] = (short)bf16rne(p1.y); \
    AF[6] = (short)bf16rne(p1.z); AF[7] = (short)bf16rne(p1.w); }
    {
        const int ar0 = rh * 32 + cl, ar1 = rh * 32 + 16 + cl;
        LDA(a00, ar0, 0) LDA(a01, ar0, 1) LDA(a02, ar0, 2) LDA(a03, ar0, 3)
        LDA(a10, ar1, 0) LDA(a11, ar1, 1) LDA(a12, ar1, 2) LDA(a13, ar1, 3)
    }
#undef LDA

    // B read addressing (round-9-verified swizzle; code&7 == cl&7)
    const int swzk = (cl & 7) << 4;
    const int inn0 = (0   + lg * 16) ^ swzk;
    const int inn1 = (64  + lg * 16) ^ swzk;
    const int inn2 = (128 + lg * 16) ^ swzk;
    const int inn3 = (192 + lg * 16) ^ swzk;

#define STAGE(DST, CH) { \
    const char* gs = (const char*)cbL + (size_t)(CH) * 16384 + t * 16; \
    char* ls = (char*)(DST) + (t & 192) * 16; \
    gld16(gs,         ls); \
    gld16(gs + 4096,  ls + 4096); \
    gld16(gs + 8192,  ls + 8192); \
    gld16(gs + 12288, ls + 12288); }

    const int tokb0 = rh * 32 + lg * 4;      // C/D row = lg*4 + reg
    const int tokb1 = tokb0 + 16;

// one chunk: 16 MFMAs (2 CTs x 2 row-tiles x 4 kt) with C-init = -cn/2,
// running per-token max (md*) + per-(token,hc) max -> chm
#define CHUNK(BUFC, CH) { \
    const char* bpA = (const char*)&Bs[BUFC][0] + (chalf * 32 + cl) * 256; \
    const int codeA = (CH) * 64 + chalf * 32 + cl; \
    const float cnA = -0.5f * cnorm[codeA]; \
    const float cnB = -0.5f * cnorm[codeA + 16]; \
    short8v b0 = *(const short8v*)(bpA + inn0); \
    short8v b1 = *(const short8v*)(bpA + inn1); \
    short8v b2 = *(const short8v*)(bpA + inn2); \
    short8v b3 = *(const short8v*)(bpA + inn3); \
    f32x4 p00 = {cnA, cnA, cnA, cnA}; \
    f32x4 p01 = {cnA, cnA, cnA, cnA}; \
    p00 = MFMA_BF16(a00, b0, p00, 0, 0, 0); \
    p00 = MFMA_BF16(a01, b1, p00, 0, 0, 0); \
    p00 = MFMA_BF16(a02, b2, p00, 0, 0, 0); \
    p00 = MFMA_BF16(a03, b3, p00, 0, 0, 0); \
    p01 = MFMA_BF16(a10, b0, p01, 0, 0, 0); \
    p01 = MFMA_BF16(a11, b1, p01, 0, 0, 0); \
    p01 = MFMA_BF16(a12, b2, p01, 0, 0, 0); \
    p01 = MFMA_BF16(a13, b3, p01, 0, 0, 0); \
    const char* bpB = bpA + 16 * 256; \
    b0 = *(const short8v*)(bpB + inn0); \
    b1 = *(const short8v*)(bpB + inn1); \
    b2 = *(const short8v*)(bpB + inn2); \
    b3 = *(const short8v*)(bpB + inn3); \
    f32x4 p10 = {cnB, cnB, cnB, cnB}; \
    f32x4 p11 = {cnB, cnB, cnB, cnB}; \
    p10 = MFMA_BF16(a00, b0, p10, 0, 0, 0); \
    p10 = MFMA_BF16(a01, b1, p10, 0, 0, 0); \
    p10 = MFMA_BF16(a02, b2, p10, 0, 0, 0); \
    p10 = MFMA_BF16(a03, b3, p10, 0, 0, 0); \
    p11 = MFMA_BF16(a10, b0, p11, 0, 0, 0); \
    p11 = MFMA_BF16(a11, b1, p11, 0, 0, 0); \
    p11 = MFMA_BF16(a12, b2, p11, 0, 0, 0); \
    p11 = MFMA_BF16(a13, b3, p11, 0, 0, 0); \
    float lm0 = fmaxf(p00[0], p10[0]); md00 = fmaxf(md00, lm0); \
    float lm1 = fmaxf(p00[1], p10[1]); md01 = fmaxf(md01, lm1); \
    float lm2 = fmaxf(p00[2], p10[2]); md02 = fmaxf(md02, lm2); \
    float lm3 = fmaxf(p00[3], p10[3]); md03 = fmaxf(md03, lm3); \
    float lm4 = fmaxf(p01[0], p11[0]); md10 = fmaxf(md10, lm4); \
    float lm5 = fmaxf(p01[1], p11[1]); md11 = fmaxf(md11, lm5); \
    float lm6 = fmaxf(p01[2], p11[2]); md12 = fmaxf(md12, lm6); \
    float lm7 = fmaxf(p01[3], p11[3]); md13 = fmaxf(md13, lm7); \
    _Pragma("unroll") \
    for (int m = 1; m < 16; m <<= 1) { \
        lm0 = fmaxf(lm0, __shfl_xor(lm0, m, 64)); \
        lm1 = fmaxf(lm1, __shfl_xor(lm1, m, 64)); \
        lm2 = fmaxf(lm2, __shfl_xor(lm2, m, 64)); \
        lm3 = fmaxf(lm3, __shfl_xor(lm3, m, 64)); \
        lm4 = fmaxf(lm4, __shfl_xor(lm4, m, 64)); \
        lm5 = fmaxf(lm5, __shfl_xor(lm5, m, 64)); \
        lm6 = fmaxf(lm6, __shfl_xor(lm6, m, 64)); \
        lm7 = fmaxf(lm7, __shfl_xor(lm7, m, 64)); \
    } \
    if (cl == 0) { \
        const int hc = (CH) * 2 + chalf; \
        chm[(tokb0 + 0) * NHC + hc] = enc16ceil(lm0); \
        chm[(tokb0 + 1) * NHC + hc] = enc16ceil(lm1); \
        chm[(tokb0 + 2) * NHC + hc] = enc16ceil(lm2); \
        chm[(tokb0 + 3) * NHC + hc] = enc16ceil(lm3); \
        chm[(tokb1 + 0) * NHC + hc] = enc16ceil(lm4); \
        chm[(tokb1 + 1) * NHC + hc] = enc16ceil(lm5); \
        chm[(tokb1 + 2) * NHC + hc] = enc16ceil(lm6); \
        chm[(tokb1 + 3) * NHC + hc] = enc16ceil(lm7); \
    } }

    // ---- PASS 1 (only pass): per-token max s + chm table ----
    STAGE(&Bs[0][0], 0)
    __syncthreads();                    // chunk0 resident; rns visible

    float md00 = -3.402823466e38f, md01 = md00, md02 = md00, md03 = md00;
    float md10 = md00, md11 = md00, md12 = md00, md13 = md00;

    for (int c2 = 0; c2 < NCHUNK / 2; ++c2) {
        const int c = c2 * 2;
        STAGE(&Bs[1][0], c + 1)
        CHUNK(0, c)
        __syncthreads();
        if (c + 2 < NCHUNK) STAGE(&Bs[0][0], c + 2)
        CHUNK(1, c + 1)
        __syncthreads();
    }
#undef CHUNK

    // ---- per-token smax: reduce md over the 16 code-lanes, cross-wave ----
#pragma unroll
    for (int m = 1; m < 16; m <<= 1) {
        md00 = fmaxf(md00, __shfl_xor(md00, m, 64));
        md01 = fmaxf(md01, __shfl_xor(md01, m, 64));
        md02 = fmaxf(md02, __shfl_xor(md02, m, 64));
        md03 = fmaxf(md03, __shfl_xor(md03, m, 64));
        md10 = fmaxf(md10, __shfl_xor(md10, m, 64));
        md11 = fmaxf(md11, __shfl_xor(md11, m, 64));
        md12 = fmaxf(md12, __shfl_xor(md12, m, 64));
        md13 = fmaxf(md13, __shfl_xor(md13, m, 64));
    }
    if (cl == 0) {
        mdw[chalf * TOKT + tokb0 + 0] = md00;
        mdw[chalf * TOKT + tokb0 + 1] = md01;
        mdw[chalf * TOKT + tokb0 + 2] = md02;
        mdw[chalf * TOKT + tokb0 + 3] = md03;
        mdw[chalf * TOKT + tokb1 + 0] = md10;
        mdw[chalf * TOKT + tokb1 + 1] = md11;
        mdw[chalf * TOKT + tokb1 + 2] = md12;
        mdw[chalf * TOKT + tokb1 + 3] = md13;
    }
    __syncthreads();

    if (t < TOKT) {
        smaxs[t] = fmaxf(mdw[t], mdw[TOKT + t]);
        best[t]  = 0xFFFFFFFFFFFFFFFFULL;
    }
    if (t == 0) *wcnt = 0;
    __syncthreads();

    // ---- qualification scan: (tok, hc) with chm >= enc16_floor(smax - M) ----
    {
        const int tok = t >> 2;
        const unsigned short th16 =
            (unsigned short)(enc32f(smaxs[tok] - MARGIN_S) >> 16);
        const int hbase = (t & 3) * 16;
#pragma unroll
        for (int k = 0; k < 16; ++k) {
            const int hc = hbase + k;
            if (chm[tok * NHC + hc] >= th16) {
                const int p = atomicAdd(wcnt, 1);
                if (p < WLCAP) wl[p] = (hc << 6) | tok;
            }
        }
    }
    __syncthreads();

    // ---- refine: exact fp32 (rounds 1-11 chain) over qualifying chunks ----
    {
        const int n   = min(*wcnt, WLCAP);
        const int sub = t & 3;
        for (int it = t >> 2; it < n; it += 64) {
            const int e   = wl[it];
            const int tok = e & 63;
            const int hc  = e >> 6;
            const float rn_t = rns[tok];
            float bd = 3.402823466e38f;
            int   bi = 0x7fffffff;
#pragma unroll
            for (int k = 0; k < 8; ++k) {
                const int code = hc * 32 + sub + k * 4;
                const float* cr = cbF + (size_t)code * EDIM;
                float dot = 0.0f;
#pragma unroll
                for (int j = 0; j < 32; ++j) {
                    const float4 a = *(const float4*)&Af[tok][j * 4];
                    const float4 b = *(const float4*)(cr + j * 4);
                    dot = fmaf(a.x, b.x, dot); dot = fmaf(a.y, b.y, dot);
                    dot = fmaf(a.z, b.z, dot); dot = fmaf(a.w, b.w, dot);
                }
                const float dd = (rn_t - 2.0f * dot) + cnorm[code];
                if (dd < bd || (dd == bd && code < bi)) { bd = dd; bi = code; }
            }
            const unsigned long long pk =
                ((unsigned long long)enc32f(bd) << 32) | (unsigned)bi;
            atomicMin(&best[tok], pk);
        }
    }
    __syncthreads();

    if (t < TOKT) {
        const int bi = (int)(best[t] & 0xFFFFFFFFu);
        idx_s[t] = bi;
        idx_out[(size_t)(tok0 + t) * NQ + level] = (float)bi;
    }
    __syncthreads();

    // ---- epilogue: gather + straight-through update + loss partial ----
    {
        const int tok = t >> 2;
        const int dq  = t & 3;
        const int gi  = idx_s[tok];
        const float* qrow = cbF + (size_t)gi * EDIM;
        float lp = 0.0f;
#pragma unroll
        for (int k = 0; k < 8; ++k) {
            const int d0 = k * 16 + dq * 4;
            const float4 q = *(const float4*)(qrow + d0);
            const float4 r = *(const float4*)&Af[tok][d0];
            float4 tq, qst, rnv;
            tq.x = q.x - r.x; tq.y = q.y - r.y; tq.z = q.z - r.z; tq.w = q.w - r.w;
            qst.x = r.x + tq.x; qst.y = r.y + tq.y;
            qst.z = r.z + tq.z; qst.w = r.w + tq.w;
            rnv.x = r.x - qst.x; rnv.y = r.y - qst.y;
            rnv.z = r.z - qst.z; rnv.w = r.w - qst.w;
            const size_t go = (size_t)(tok0 + tok) * EDIM + d0;
            *(float4*)(rout + go) = rnv;
            if (first) {
                *(float4*)(xq + go) = qst;
            } else {
                float4 o = *(const float4*)(xq + go);
                o.x += qst.x; o.y += qst.y; o.z += qst.z; o.w += qst.w;
                *(float4*)(xq + go) = o;
            }
            lp += tq.x * tq.x; lp += tq.y * tq.y;
            lp += tq.z * tq.z; lp += tq.w * tq.w;
        }
        lsum[t] = lp;
    }
    __syncthreads();
#pragma unroll
    for (int s2 = 128; s2 > 0; s2 >>= 1) {
        if (t < s2) lsum[t] += lsum[t + s2];
        __syncthreads();
    }
    if (t == 0) atomicAdd(loss_accum, lsum[0]);
}

// ---------------------------------------------------------------------------
__global__ void finalize_kernel(const float* __restrict__ loss_accum,
                                float* __restrict__ out_loss)
{
    *out_loss = *loss_accum * (1.25f / (4.0f * (float)NTOK * (float)EDIM));
}

extern "C" void kernel_launch(void* const* d_in, const int* in_sizes, int n_in,
                              void* d_out, int out_size, void* d_ws, size_t ws_size,
                              hipStream_t stream)
{
    const float* x  = (const float*)d_in[0];
    const float* cb = (const float*)d_in[1];

    float* out      = (float*)d_out;
    float* xq       = out;
    float* out_loss = out + (size_t)NTOK * EDIM;
    float* idx_out  = out + (size_t)NTOK * EDIM + 1;

    float* ws             = (float*)d_ws;
    float* cnorm          = ws;                            // NQ*NE
    float* loss_accum     = ws + 8192;
    unsigned short* cb16s = (unsigned short*)(ws + 8448);  // NQ*NE*EDIM bf16
    float* r0             = ws + 8448 + (size_t)NQ * NE * EDIM / 2;

    prep_kernel<<<(NQ * NE) / 256, 256, 0, stream>>>(cb, cb16s, cnorm, loss_accum);

    for (int l = 0; l < NQ; ++l) {
        const float* rin = (l == 0) ? x : r0;
        vq_level_kernel<<<NTOK / TOKT, 256, 0, stream>>>(
            rin, cb + (size_t)l * NE * EDIM,
            cb16s + (size_t)l * NE * EDIM,
            cnorm + (size_t)l * NE,
            r0, xq, idx_out, loss_accum, l, (l == 0) ? 1 : 0);
    }
    finalize_kernel<<<1, 1, 0, stream>>>(loss_accum, out_loss);
}

// Round 13
// 313.741 us; speedup vs baseline: 2.8337x; 2.8337x over previous
//
#include <hip/hip_runtime.h>

#define NTOK 32768
#define NE   2048
#define EDIM 128
#define NQ   4

#define TOKT 64                  // tokens per block
#define CHCODES 128              // codes per staged chunk (32 KB bf16)
#define NCHUNK (NE / CHCODES)    // 16
#define CAP 16
#define MARGIN_S 0.1875f         // s-space margin (~2.9x bf16 error bound)

typedef __attribute__((ext_vector_type(8))) short short8v;   // 8 bf16
typedef __attribute__((ext_vector_type(4))) float f32x4;

__device__ __forceinline__ unsigned short bf16rne(float x) {
    unsigned u = __float_as_uint(x);
    unsigned r = 0x7FFFu + ((u >> 16) & 1u);
    return (unsigned short)((u + r) >> 16);
}

__device__ __forceinline__ void gld16(const void* g, const void* l) {
    __builtin_amdgcn_global_load_lds(
        (const __attribute__((address_space(1))) unsigned int*)g,
        (__attribute__((address_space(3))) unsigned int*)l, 16, 0, 0);
}

#define MFMA_BF16 __builtin_amdgcn_mfma_f32_16x16x32_bf16

// ---------------------------------------------------------------------------
// prep: per-code fp32 norms (identical serial chain to rounds 1-12) + bf16
// convert with dim-XOR swizzle (dim ^ ((code&7)<<3)) + zero loss accumulator.
// ---------------------------------------------------------------------------
__global__ __launch_bounds__(256) void prep_kernel(
    const float* __restrict__ cb, unsigned short* __restrict__ cb16s,
    float* __restrict__ cnorm, float* __restrict__ loss_accum)
{
    const int row = blockIdx.x * 256 + threadIdx.x;   // 0..NQ*NE-1
    if (row == 0) *loss_accum = 0.0f;
    const float* src = cb + (size_t)row * EDIM;
    unsigned short* dst = cb16s + (size_t)row * EDIM;
    const int swz8 = (row & 7) << 3;
    float s = 0.0f;
#pragma unroll
    for (int j = 0; j < EDIM / 4; ++j) {
        float4 v = ((const float4*)src)[j];
        s += v.x * v.x; s += v.y * v.y; s += v.z * v.z; s += v.w * v.w;
        ushort4 o;
        o.x = bf16rne(v.x); o.y = bf16rne(v.y);
        o.z = bf16rne(v.z); o.w = bf16rne(v.w);
        *(ushort4*)(dst + ((j * 4) ^ swz8)) = o;
    }
    cnorm[row] = s;
}

// ---------------------------------------------------------------------------
// One VQ level. 2-pass bf16-MFMA sieve (s = dot - cn/2 via C-init) + exact
// fp32 refine. 256 thr / 4 waves; wave w = code-quarter x ALL 64 tokens
// (4 row-tiles, 16 A-frags in regs) -> 8 ds_read_b128 per 32 MFMAs (2x
// round-11 reuse), CHCODES=128 halves barrier count. No Af LDS copy:
// residual read from global (L2-hot). ~75.8 KB LDS -> 2 blocks/CU.
// ---------------------------------------------------------------------------
__global__ __launch_bounds__(256, 2) void vq_level_kernel(
    const float* __restrict__ rin,
    const float* __restrict__ cbF,          // fp32 codebook (refine + gather)
    const unsigned short* __restrict__ cbL, // bf16 swizzled codebook (level)
    const float* __restrict__ cnorm,        // [NE]
    float* __restrict__ rout,
    float* __restrict__ xq,
    float* __restrict__ idx_out,
    float* __restrict__ loss_accum,
    int level, int first)
{
    __shared__ __align__(16) unsigned short Bs[2][CHCODES * EDIM]; // 65536 B
    __shared__ float part[4 * TOKT];
    __shared__ float rns[TOKT];
    __shared__ float mdw[4][TOKT];
    __shared__ float smaxs[TOKT];
    __shared__ int   cnt[TOKT];
    __shared__ int   lst[TOKT * CAP];
    __shared__ float redb_d[4][TOKT];
    __shared__ int   redb_i[4][TOKT];
    __shared__ int   idx_s[TOKT];
    __shared__ float lsum[256];

    const int t    = threadIdx.x;
    const int tok0 = blockIdx.x * TOKT;
    const int w    = t >> 6;          // wave = code quarter
    const int cl   = t & 15;          // MFMA col lane (code)
    const int lg   = (t & 63) >> 4;   // k-group
    if (t < TOKT) cnt[t] = 0;

    // ---- token norms from global rin (rounds 1-12 association) ----
    {
        const int tok = t & 63;
        const int dg  = t >> 6;
        float s = 0.0f;
#pragma unroll
        for (int j = 0; j < 8; ++j) {
            const int d0 = dg * 32 + j * 4;
            float4 v = *(const float4*)(rin + (size_t)(tok0 + tok) * EDIM + d0);
            s += v.x * v.x; s += v.y * v.y; s += v.z * v.z; s += v.w * v.w;
        }
        part[dg * TOKT + tok] = s;
    }
    __syncthreads();
    if (t < TOKT)
        rns[t] = ((part[t] + part[TOKT + t]) + part[2 * TOKT + t])
                 + part[3 * TOKT + t];

    // ---- A fragments: 4 row-tiles x 4 kt, straight from global rin ----
    short8v a00, a01, a02, a03, a10, a11, a12, a13;
    short8v a20, a21, a22, a23, a30, a31, a32, a33;
#define LDA(AF, RT, KT) { \
    const float* ap = rin + (size_t)(tok0 + (RT) * 16 + cl) * EDIM \
                      + (KT) * 32 + lg * 8; \
    float4 q0 = *(const float4*)ap; float4 q1 = *(const float4*)(ap + 4); \
    AF[0] = (short)bf16rne(q0.x); AF[1] = (short)bf16rne(q0.y); \
    AF[2] = (short)bf16rne(q0.z); AF[3] = (short)bf16rne(q0.w); \
    AF[4] = (short)bf16rne(q1.x); AF[5] = (short)bf16rne(q1.y); \
    AF[6] = (short)bf16rne(q1.z); AF[7] = (short)bf16rne(q1.w); }
    LDA(a00, 0, 0) LDA(a01, 0, 1) LDA(a02, 0, 2) LDA(a03, 0, 3)
    LDA(a10, 1, 0) LDA(a11, 1, 1) LDA(a12, 1, 2) LDA(a13, 1, 3)
    LDA(a20, 2, 0) LDA(a21, 2, 1) LDA(a22, 2, 2) LDA(a23, 2, 3)
    LDA(a30, 3, 0) LDA(a31, 3, 1) LDA(a32, 3, 2) LDA(a33, 3, 3)
#undef LDA

    // B read addressing (round-9-verified swizzle; code&7 == cl&7)
    const int swzk = (cl & 7) << 4;
    const int inn0 = (0   + lg * 16) ^ swzk;
    const int inn1 = (64  + lg * 16) ^ swzk;
    const int inn2 = (128 + lg * 16) ^ swzk;
    const int inn3 = (192 + lg * 16) ^ swzk;

    // token bases for the 4 row-tiles (C/D row = lg*4 + reg)
    const int tb0 = lg * 4, tb1 = 16 + lg * 4, tb2 = 32 + lg * 4, tb3 = 48 + lg * 4;

#define STAGE(DST, CH) { \
    const char* gs = (const char*)cbL + (size_t)(CH) * 32768 + t * 16; \
    char* ls = (char*)(DST) + (t & 192) * 16; \
    gld16(gs,          ls); \
    gld16(gs + 4096,   ls + 4096); \
    gld16(gs + 8192,   ls + 8192); \
    gld16(gs + 12288,  ls + 12288); \
    gld16(gs + 16384,  ls + 16384); \
    gld16(gs + 20480,  ls + 20480); \
    gld16(gs + 24576,  ls + 24576); \
    gld16(gs + 28672,  ls + 28672); }

// one 16-code column tile: 4 b128 reads feed 16 MFMAs (4 row-tiles)
#define CTBLK(BUFC, CH, CT, TAIL) { \
    const int code = (CH) * CHCODES + w * 32 + (CT) * 16 + cl; \
    const float cn2 = -0.5f * cnorm[code]; \
    const char* bp = (const char*)&Bs[BUFC][0] \
                     + (w * 32 + (CT) * 16 + cl) * 256; \
    f32x4 p0 = {cn2, cn2, cn2, cn2}; f32x4 p1 = p0; \
    f32x4 p2 = p0;                   f32x4 p3 = p0; \
    short8v bb; \
    bb = *(const short8v*)(bp + inn0); \
    p0 = MFMA_BF16(a00, bb, p0, 0, 0, 0); p1 = MFMA_BF16(a10, bb, p1, 0, 0, 0); \
    p2 = MFMA_BF16(a20, bb, p2, 0, 0, 0); p3 = MFMA_BF16(a30, bb, p3, 0, 0, 0); \
    bb = *(const short8v*)(bp + inn1); \
    p0 = MFMA_BF16(a01, bb, p0, 0, 0, 0); p1 = MFMA_BF16(a11, bb, p1, 0, 0, 0); \
    p2 = MFMA_BF16(a21, bb, p2, 0, 0, 0); p3 = MFMA_BF16(a31, bb, p3, 0, 0, 0); \
    bb = *(const short8v*)(bp + inn2); \
    p0 = MFMA_BF16(a02, bb, p0, 0, 0, 0); p1 = MFMA_BF16(a12, bb, p1, 0, 0, 0); \
    p2 = MFMA_BF16(a22, bb, p2, 0, 0, 0); p3 = MFMA_BF16(a32, bb, p3, 0, 0, 0); \
    bb = *(const short8v*)(bp + inn3); \
    p0 = MFMA_BF16(a03, bb, p0, 0, 0, 0); p1 = MFMA_BF16(a13, bb, p1, 0, 0, 0); \
    p2 = MFMA_BF16(a23, bb, p2, 0, 0, 0); p3 = MFMA_BF16(a33, bb, p3, 0, 0, 0); \
    TAIL }

#define T_MIN \
    md00 = fmaxf(md00, p0[0]); md01 = fmaxf(md01, p0[1]); \
    md02 = fmaxf(md02, p0[2]); md03 = fmaxf(md03, p0[3]); \
    md10 = fmaxf(md10, p1[0]); md11 = fmaxf(md11, p1[1]); \
    md12 = fmaxf(md12, p1[2]); md13 = fmaxf(md13, p1[3]); \
    md20 = fmaxf(md20, p2[0]); md21 = fmaxf(md21, p2[1]); \
    md22 = fmaxf(md22, p2[2]); md23 = fmaxf(md23, p2[3]); \
    md30 = fmaxf(md30, p3[0]); md31 = fmaxf(md31, p3[1]); \
    md32 = fmaxf(md32, p3[2]); md33 = fmaxf(md33, p3[3]);

#define PUSH1(S, TH, TOK) { if ((S) > (TH)) { \
    int pp = atomicAdd(&cnt[TOK], 1); \
    if (pp < CAP) lst[(TOK) * CAP + pp] = code; } }
#define T_PUSH \
    PUSH1(p0[0], th00, tb0 + 0) PUSH1(p0[1], th01, tb0 + 1) \
    PUSH1(p0[2], th02, tb0 + 2) PUSH1(p0[3], th03, tb0 + 3) \
    PUSH1(p1[0], th10, tb1 + 0) PUSH1(p1[1], th11, tb1 + 1) \
    PUSH1(p1[2], th12, tb1 + 2) PUSH1(p1[3], th13, tb1 + 3) \
    PUSH1(p2[0], th20, tb2 + 0) PUSH1(p2[1], th21, tb2 + 1) \
    PUSH1(p2[2], th22, tb2 + 2) PUSH1(p2[3], th23, tb2 + 3) \
    PUSH1(p3[0], th30, tb3 + 0) PUSH1(p3[1], th31, tb3 + 1) \
    PUSH1(p3[2], th32, tb3 + 2) PUSH1(p3[3], th33, tb3 + 3)

#define CH_P1(B, CH) { CTBLK(B, CH, 0, T_MIN)  CTBLK(B, CH, 1, T_MIN)  }
#define CH_P2(B, CH) { CTBLK(B, CH, 0, T_PUSH) CTBLK(B, CH, 1, T_PUSH) }

    // ---- PASS 1: per-token max of s = dot - cn/2 ----
    STAGE(&Bs[0][0], 0)
    __syncthreads();

    float md00 = -3.402823466e38f, md01 = md00, md02 = md00, md03 = md00;
    float md10 = md00, md11 = md00, md12 = md00, md13 = md00;
    float md20 = md00, md21 = md00, md22 = md00, md23 = md00;
    float md30 = md00, md31 = md00, md32 = md00, md33 = md00;

    for (int c2 = 0; c2 < NCHUNK / 2; ++c2) {
        const int c = c2 * 2;
        STAGE(&Bs[1][0], c + 1)
        CH_P1(0, c)
        __syncthreads();
        if (c + 2 < NCHUNK) STAGE(&Bs[0][0], c + 2)
        CH_P1(1, c + 1)
        __syncthreads();
    }

    // stage pass-2 chunk 0 now; it drains across the next two barriers
    STAGE(&Bs[0][0], 0)

    // once-per-pass reduce over the 16 code-lanes
#pragma unroll
    for (int m = 1; m < 16; m <<= 1) {
        md00 = fmaxf(md00, __shfl_xor(md00, m, 64));
        md01 = fmaxf(md01, __shfl_xor(md01, m, 64));
        md02 = fmaxf(md02, __shfl_xor(md02, m, 64));
        md03 = fmaxf(md03, __shfl_xor(md03, m, 64));
        md10 = fmaxf(md10, __shfl_xor(md10, m, 64));
        md11 = fmaxf(md11, __shfl_xor(md11, m, 64));
        md12 = fmaxf(md12, __shfl_xor(md12, m, 64));
        md13 = fmaxf(md13, __shfl_xor(md13, m, 64));
        md20 = fmaxf(md20, __shfl_xor(md20, m, 64));
        md21 = fmaxf(md21, __shfl_xor(md21, m, 64));
        md22 = fmaxf(md22, __shfl_xor(md22, m, 64));
        md23 = fmaxf(md23, __shfl_xor(md23, m, 64));
        md30 = fmaxf(md30, __shfl_xor(md30, m, 64));
        md31 = fmaxf(md31, __shfl_xor(md31, m, 64));
        md32 = fmaxf(md32, __shfl_xor(md32, m, 64));
        md33 = fmaxf(md33, __shfl_xor(md33, m, 64));
    }
    if (cl == 0) {
        mdw[w][tb0 + 0] = md00; mdw[w][tb0 + 1] = md01;
        mdw[w][tb0 + 2] = md02; mdw[w][tb0 + 3] = md03;
        mdw[w][tb1 + 0] = md10; mdw[w][tb1 + 1] = md11;
        mdw[w][tb1 + 2] = md12; mdw[w][tb1 + 3] = md13;
        mdw[w][tb2 + 0] = md20; mdw[w][tb2 + 1] = md21;
        mdw[w][tb2 + 2] = md22; mdw[w][tb2 + 3] = md23;
        mdw[w][tb3 + 0] = md30; mdw[w][tb3 + 1] = md31;
        mdw[w][tb3 + 2] = md32; mdw[w][tb3 + 3] = md33;
    }
    __syncthreads();
    if (t < TOKT)
        smaxs[t] = fmaxf(fmaxf(mdw[0][t], mdw[1][t]),
                         fmaxf(mdw[2][t], mdw[3][t]));
    __syncthreads();

    const float th00 = smaxs[tb0 + 0] - MARGIN_S;
    const float th01 = smaxs[tb0 + 1] - MARGIN_S;
    const float th02 = smaxs[tb0 + 2] - MARGIN_S;
    const float th03 = smaxs[tb0 + 3] - MARGIN_S;
    const float th10 = smaxs[tb1 + 0] - MARGIN_S;
    const float th11 = smaxs[tb1 + 1] - MARGIN_S;
    const float th12 = smaxs[tb1 + 2] - MARGIN_S;
    const float th13 = smaxs[tb1 + 3] - MARGIN_S;
    const float th20 = smaxs[tb2 + 0] - MARGIN_S;
    const float th21 = smaxs[tb2 + 1] - MARGIN_S;
    const float th22 = smaxs[tb2 + 2] - MARGIN_S;
    const float th23 = smaxs[tb2 + 3] - MARGIN_S;
    const float th30 = smaxs[tb3 + 0] - MARGIN_S;
    const float th31 = smaxs[tb3 + 1] - MARGIN_S;
    const float th32 = smaxs[tb3 + 2] - MARGIN_S;
    const float th33 = smaxs[tb3 + 3] - MARGIN_S;

    // ---- PASS 2: collect candidates within margin ----
    for (int c2 = 0; c2 < NCHUNK / 2; ++c2) {
        const int c = c2 * 2;
        STAGE(&Bs[1][0], c + 1)
        CH_P2(0, c)
        __syncthreads();
        if (c + 2 < NCHUNK) STAGE(&Bs[0][0], c + 2)
        CH_P2(1, c + 1)
        __syncthreads();
    }

    // ---- refine: exact fp32 (rounds 1-12 chain), 4-way per token ----
    {
        const int tok = t & 63;
        const int s   = t >> 6;
        const int n   = min(cnt[tok], CAP);
        const float rn_t = rns[tok];
        const float* rrow = rin + (size_t)(tok0 + tok) * EDIM;
        float bd = 3.402823466e38f;
        int   bi = 0x7fffffff;
        for (int i = s; i < n; i += 4) {
            const int c = lst[tok * CAP + i];
            const float* cr = cbF + (size_t)c * EDIM;
            float dot = 0.0f;
#pragma unroll
            for (int j = 0; j < 32; ++j) {
                const float4 a = *(const float4*)(rrow + j * 4);
                const float4 b = *(const float4*)(cr + j * 4);
                dot = fmaf(a.x, b.x, dot); dot = fmaf(a.y, b.y, dot);
                dot = fmaf(a.z, b.z, dot); dot = fmaf(a.w, b.w, dot);
            }
            const float dd = (rn_t - 2.0f * dot) + cnorm[c];
            if (dd < bd || (dd == bd && c < bi)) { bd = dd; bi = c; }
        }
        redb_d[s][tok] = bd;
        redb_i[s][tok] = bi;
    }
    __syncthreads();
    if (t < TOKT) {
        float bd = redb_d[0][t];
        int   bi = redb_i[0][t];
#pragma unroll
        for (int s = 1; s < 4; ++s) {
            const float dd = redb_d[s][t];
            const int   ii = redb_i[s][t];
            if (dd < bd || (dd == bd && ii < bi)) { bd = dd; bi = ii; }
        }
        idx_s[t] = bi;
        idx_out[(size_t)(tok0 + t) * NQ + level] = (float)bi;
    }
    __syncthreads();

    // ---- epilogue: gather + straight-through update + loss partial ----
    {
        const int tok = t >> 2;
        const int dq  = t & 3;
        const int gi  = idx_s[tok];
        const float* qrow = cbF + (size_t)gi * EDIM;
        const float* rrow = rin + (size_t)(tok0 + tok) * EDIM;
        float lp = 0.0f;
#pragma unroll
        for (int k = 0; k < 8; ++k) {
            const int d0 = k * 16 + dq * 4;
            const float4 q = *(const float4*)(qrow + d0);
            const float4 r = *(const float4*)(rrow + d0);
            float4 tq, qst, rnv;
            tq.x = q.x - r.x; tq.y = q.y - r.y; tq.z = q.z - r.z; tq.w = q.w - r.w;
            qst.x = r.x + tq.x; qst.y = r.y + tq.y;
            qst.z = r.z + tq.z; qst.w = r.w + tq.w;
            rnv.x = r.x - qst.x; rnv.y = r.y - qst.y;
            rnv.z = r.z - qst.z; rnv.w = r.w - qst.w;
            const size_t go = (size_t)(tok0 + tok) * EDIM + d0;
            *(float4*)(rout + go) = rnv;
            if (first) {
                *(float4*)(xq + go) = qst;
            } else {
                float4 o = *(const float4*)(xq + go);
                o.x += qst.x; o.y += qst.y; o.z += qst.z; o.w += qst.w;
                *(float4*)(xq + go) = o;
            }
            lp += tq.x * tq.x; lp += tq.y * tq.y;
            lp += tq.z * tq.z; lp += tq.w * tq.w;
        }
        lsum[t] = lp;
    }
    __syncthreads();
#pragma unroll
    for (int s2 = 128; s2 > 0; s2 >>= 1) {
        if (t < s2) lsum[t] += lsum[t + s2];
        __syncthreads();
    }
    if (t == 0) atomicAdd(loss_accum, lsum[0]);
}

// ---------------------------------------------------------------------------
__global__ void finalize_kernel(const float* __restrict__ loss_accum,
                                float* __restrict__ out_loss)
{
    *out_loss = *loss_accum * (1.25f / (4.0f * (float)NTOK * (float)EDIM));
}

extern "C" void kernel_launch(void* const* d_in, const int* in_sizes, int n_in,
                              void* d_out, int out_size, void* d_ws, size_t ws_size,
                              hipStream_t stream)
{
    const float* x  = (const float*)d_in[0];
    const float* cb = (const float*)d_in[1];

    float* out      = (float*)d_out;
    float* xq       = out;
    float* out_loss = out + (size_t)NTOK * EDIM;
    float* idx_out  = out + (size_t)NTOK * EDIM + 1;

    float* ws             = (float*)d_ws;
    float* cnorm          = ws;                            // NQ*NE
    float* loss_accum     = ws + 8192;
    unsigned short* cb16s = (unsigned short*)(ws + 8448);  // NQ*NE*EDIM bf16
    float* r0             = ws + 8448 + (size_t)NQ * NE * EDIM / 2;

    prep_kernel<<<(NQ * NE) / 256, 256, 0, stream>>>(cb, cb16s, cnorm, loss_accum);

    for (int l = 0; l < NQ; ++l) {
        const float* rin = (l == 0) ? x : r0;
        vq_level_kernel<<<NTOK / TOKT, 256, 0, stream>>>(
            rin, cb + (size_t)l * NE * EDIM,
            cb16s + (size_t)l * NE * EDIM,
            cnorm + (size_t)l * NE,
            r0, xq, idx_out, loss_accum, l, (l == 0) ? 1 : 0);
    }
    finalize_kernel<<<1, 1, 0, stream>>>(loss_accum, out_loss);
}